// Round 3
// baseline (410.426 us; speedup 1.0000x reference)
//
#include <hip/hip_runtime.h>
#include <hip/hip_bf16.h>

#define NROWS 8192
#define KD    1024

typedef __attribute__((ext_vector_type(8))) short bf16x8;
typedef __attribute__((ext_vector_type(4))) float f32x4;

__device__ unsigned short g_x1n[(size_t)NROWS * KD];
__device__ unsigned short g_x2n[(size_t)NROWS * KD];

__device__ __forceinline__ unsigned short f2bf(float f) {
    union { float f; unsigned u; } x; x.f = f;
    return (unsigned short)((x.u + 0x7fffu + ((x.u >> 16) & 1u)) >> 16);  // RNE
}

__global__ __launch_bounds__(256) void norm_cast_kernel(const float* __restrict__ x1,
                                                        const float* __restrict__ x2) {
    int row = blockIdx.x;
    const float* src;
    unsigned short* dst;
    if (row < NROWS) { src = x1 + (size_t)row * KD;           dst = g_x1n + (size_t)row * KD; }
    else             { src = x2 + (size_t)(row - NROWS) * KD; dst = g_x2n + (size_t)(row - NROWS) * KD; }

    int t = threadIdx.x;
    float4 v = ((const float4*)src)[t];
    float s = v.x * v.x + v.y * v.y + v.z * v.z + v.w * v.w;
    #pragma unroll
    for (int off = 32; off > 0; off >>= 1) s += __shfl_down(s, off);

    __shared__ float red[4];
    if ((t & 63) == 0) red[t >> 6] = s;
    __syncthreads();
    float tot = red[0] + red[1] + red[2] + red[3];
    float inv = 1.0f / fmaxf(sqrtf(tot), 1e-8f);

    ushort4 o;
    o.x = f2bf(v.x * inv); o.y = f2bf(v.y * inv);
    o.z = f2bf(v.z * inv); o.w = f2bf(v.w * inv);
    ((ushort4*)dst)[t] = o;
}

__device__ __forceinline__ void gload_lds16(const unsigned short* g, unsigned short* l) {
    __builtin_amdgcn_global_load_lds((const __attribute__((address_space(1))) void*)g,
                                     (__attribute__((address_space(3))) void*)l,
                                     16, 0, 0);
}

#define BARX() do { asm volatile("" ::: "memory"); __builtin_amdgcn_s_barrier(); \
                    asm volatile("" ::: "memory"); } while (0)
#define SGB0() __builtin_amdgcn_sched_barrier(0)
#define MFMA16(a, b, c) __builtin_amdgcn_mfma_f32_16x16x32_bf16((a), (b), (c), 0, 0, 0)

struct Ctx {
    const unsigned short* srcA;   // g_x1n + bm*256*KD + trow*KD + scol
    const unsigned short* srcB;
    unsigned short* ldsf;
    int ldst;                     // t*8 (stage dest elem offset within region)
    int aoff0, aoff1, boff0, boff1;
    int wr, wch;
};

// Stage one half-tile (128 rows x 64 k): 2 x global_load_lds(16B) per thread.
// LDS dest LINEAR; the global source carries the inverse swizzle (in srcA/srcB).
__device__ __forceinline__ void stage_half(const Ctx& c, bool isA, int hbit, int region, int Tk) {
    const unsigned short* src = (isA ? c.srcA : c.srcB) + (size_t)hbit * 128 * KD + Tk * 64;
    unsigned short* dst = c.ldsf + region * 8192 + c.ldst;
    gload_lds16(src, dst);
    gload_lds16(src + (size_t)64 * KD, dst + 4096);
}

// One K-tile = 4 sections. Reads in section p feed the MFMA of section p+1.
// MODE 0: steady (stage T+2, vmcnt(4));  1: tile NT-2 (no stage, vmcnt(0));
// MODE 2: last tile (no stage, no vmcnt, no next-A read).
template<int BUF, int MODE>
__device__ __forceinline__ void tile_body(const Ctx& c, f32x4 (&acc)[8][4],
                                          bf16x8 (&Aa)[8], bf16x8 (&Ab)[8],
                                          bf16x8 (&Ba)[4], bf16x8 (&Bb)[4], int T) {
    const unsigned short* ab  = c.ldsf + (BUF * 4 + c.wr) * 8192;
    const unsigned short* bb  = c.ldsf + (BUF * 4 + 2 + c.wch) * 8192;
    const unsigned short* abn = c.ldsf + ((BUF ^ 1) * 4 + c.wr) * 8192;

    // ---- S0: read Ba(ni0-1) + Bb(ni2-3); MFMA Aa x Ba ----
    #pragma unroll
    for (int ni = 0; ni < 2; ++ni) {
        Ba[ni * 2 + 0] = *(const bf16x8*)(bb + ni * 1024 + c.boff0);
        Ba[ni * 2 + 1] = *(const bf16x8*)(bb + ni * 1024 + c.boff1);
    }
    #pragma unroll
    for (int ni = 0; ni < 2; ++ni) {
        Bb[ni * 2 + 0] = *(const bf16x8*)(bb + (ni + 2) * 1024 + c.boff0);
        Bb[ni * 2 + 1] = *(const bf16x8*)(bb + (ni + 2) * 1024 + c.boff1);
    }
    BARX(); SGB0();
    __builtin_amdgcn_s_setprio(1);
    #pragma unroll
    for (int mi = 0; mi < 4; ++mi)
        #pragma unroll
        for (int ni = 0; ni < 2; ++ni) {
            acc[mi][ni] = MFMA16(Aa[mi * 2 + 0], Ba[ni * 2 + 0], acc[mi][ni]);
            acc[mi][ni] = MFMA16(Aa[mi * 2 + 1], Ba[ni * 2 + 1], acc[mi][ni]);
        }
    __builtin_amdgcn_s_setprio(0);
    BARX();

    // ---- S1: read Ab(mi4-7); MFMA Aa x Bb ----
    #pragma unroll
    for (int mi = 0; mi < 4; ++mi) {
        Ab[mi * 2 + 0] = *(const bf16x8*)(ab + (mi + 4) * 1024 + c.aoff0);
        Ab[mi * 2 + 1] = *(const bf16x8*)(ab + (mi + 4) * 1024 + c.aoff1);
    }
    BARX(); SGB0();
    __builtin_amdgcn_s_setprio(1);
    #pragma unroll
    for (int mi = 0; mi < 4; ++mi)
        #pragma unroll
        for (int ni = 0; ni < 2; ++ni) {
            acc[mi][ni + 2] = MFMA16(Aa[mi * 2 + 0], Bb[ni * 2 + 0], acc[mi][ni + 2]);
            acc[mi][ni + 2] = MFMA16(Aa[mi * 2 + 1], Bb[ni * 2 + 1], acc[mi][ni + 2]);
        }
    __builtin_amdgcn_s_setprio(0);
    BARX();

    // ---- S2: stage (T+2).B0,B1; MFMA Ab x Bb; vmcnt ----
    if (MODE == 0) {
        stage_half(c, false, 0, BUF * 4 + 2, T + 2);
        stage_half(c, false, 1, BUF * 4 + 3, T + 2);
    }
    BARX(); SGB0();
    __builtin_amdgcn_s_setprio(1);
    #pragma unroll
    for (int mi = 0; mi < 4; ++mi)
        #pragma unroll
        for (int ni = 0; ni < 2; ++ni) {
            acc[mi + 4][ni + 2] = MFMA16(Ab[mi * 2 + 0], Bb[ni * 2 + 0], acc[mi + 4][ni + 2]);
            acc[mi + 4][ni + 2] = MFMA16(Ab[mi * 2 + 1], Bb[ni * 2 + 1], acc[mi + 4][ni + 2]);
        }
    __builtin_amdgcn_s_setprio(0);
    if (MODE == 0)      asm volatile("s_waitcnt vmcnt(4)" ::: "memory");
    else if (MODE == 1) asm volatile("s_waitcnt vmcnt(0)" ::: "memory");
    BARX();

    // ---- S3: read next-tile Aa(mi0-3); stage (T+2).A0,A1; MFMA Ab x Ba ----
    if (MODE <= 1) {
        #pragma unroll
        for (int mi = 0; mi < 4; ++mi) {
            Aa[mi * 2 + 0] = *(const bf16x8*)(abn + mi * 1024 + c.aoff0);
            Aa[mi * 2 + 1] = *(const bf16x8*)(abn + mi * 1024 + c.aoff1);
        }
    }
    if (MODE == 0) {
        stage_half(c, true, 0, BUF * 4 + 0, T + 2);
        stage_half(c, true, 1, BUF * 4 + 1, T + 2);
    }
    BARX(); SGB0();
    __builtin_amdgcn_s_setprio(1);
    #pragma unroll
    for (int mi = 0; mi < 4; ++mi)
        #pragma unroll
        for (int ni = 0; ni < 2; ++ni) {
            acc[mi + 4][ni] = MFMA16(Ab[mi * 2 + 0], Ba[ni * 2 + 0], acc[mi + 4][ni]);
            acc[mi + 4][ni] = MFMA16(Ab[mi * 2 + 1], Ba[ni * 2 + 1], acc[mi + 4][ni]);
        }
    __builtin_amdgcn_s_setprio(0);
    BARX();
}

// 256x256 tile, BK=64, 8 waves (2M x 4N), read-ahead pipelined 8-phase schedule.
__global__ __launch_bounds__(512, 2) void gemm8_kernel(float* __restrict__ C) {
    __shared__ unsigned short lds[2][4][8192];   // 128 KiB

    int bid = blockIdx.x;                 // 1024 blocks, 1024 % 8 == 0
    int swz = (bid & 7) * 128 + (bid >> 3);
    int bm = swz >> 5, bn = swz & 31;

    int t = threadIdx.x;
    int lane = t & 63, wid = t >> 6;
    int wr = wid >> 2, wc = wid & 3;
    int r = lane & 15;
    int s0 = (lane >> 4) ^ (r & 7);
    int s1 = s0 ^ 4;

    Ctx c;
    {
        int trow = t >> 3;
        int scol = ((t & 7) ^ (trow & 7)) * 8;
        c.srcA = g_x1n + (size_t)bm * 256 * KD + (size_t)trow * KD + scol;
        c.srcB = g_x2n + (size_t)bn * 256 * KD + (size_t)trow * KD + scol;
    }
    c.ldsf = &lds[0][0][0];
    c.ldst = t * 8;
    c.aoff0 = r * 64 + s0 * 8;
    c.aoff1 = r * 64 + s1 * 8;
    c.boff0 = ((wc & 1) * 64 + r) * 64 + s0 * 8;
    c.boff1 = ((wc & 1) * 64 + r) * 64 + s1 * 8;
    c.wr = wr;
    c.wch = wc >> 1;

    f32x4 acc[8][4] = {};
    bf16x8 Aa[8], Ab[8], Ba[4], Bb[4];

    // Prologue: stage tiles 0 and 1 fully; wait tile 0; preload Aa(tile0, mi0-3).
    stage_half(c, false, 0, 2, 0); stage_half(c, false, 1, 3, 0);
    stage_half(c, true,  0, 0, 0); stage_half(c, true,  1, 1, 0);
    stage_half(c, false, 0, 6, 1); stage_half(c, false, 1, 7, 1);
    stage_half(c, true,  0, 4, 1); stage_half(c, true,  1, 5, 1);
    asm volatile("s_waitcnt vmcnt(8)" ::: "memory");
    BARX();
    {
        const unsigned short* ab0 = c.ldsf + c.wr * 8192;
        #pragma unroll
        for (int mi = 0; mi < 4; ++mi) {
            Aa[mi * 2 + 0] = *(const bf16x8*)(ab0 + mi * 1024 + c.aoff0);
            Aa[mi * 2 + 1] = *(const bf16x8*)(ab0 + mi * 1024 + c.aoff1);
        }
    }

    for (int it = 0; it < 7; ++it) {      // tiles 0..13
        tile_body<0, 0>(c, acc, Aa, Ab, Ba, Bb, 2 * it);
        tile_body<1, 0>(c, acc, Aa, Ab, Ba, Bb, 2 * it + 1);
    }
    tile_body<0, 1>(c, acc, Aa, Ab, Ba, Bb, 14);
    tile_body<1, 2>(c, acc, Aa, Ab, Ba, Bb, 15);

    // Epilogue: C/D layout col = lane&15, row = (lane>>4)*4 + j
    int cn = lane & 15, rq = (lane >> 4) * 4;
    int rbase = bm * 256 + wr * 128;
    int cbase = bn * 256 + wc * 64;
    #pragma unroll
    for (int mi = 0; mi < 8; ++mi)
        #pragma unroll
        for (int ni = 0; ni < 4; ++ni)
            #pragma unroll
            for (int j = 0; j < 4; ++j)
                C[(size_t)(rbase + mi * 16 + rq + j) * NROWS + cbase + ni * 16 + cn] =
                    acc[mi][ni][j] * 20.0f;
}

extern "C" void kernel_launch(void* const* d_in, const int* in_sizes, int n_in,
                              void* d_out, int out_size, void* d_ws, size_t ws_size,
                              hipStream_t stream) {
    (void)in_sizes; (void)n_in; (void)d_ws; (void)ws_size; (void)out_size;
    const float* x1 = (const float*)d_in[0];
    const float* x2 = (const float*)d_in[1];
    float* out = (float*)d_out;

    norm_cast_kernel<<<2 * NROWS, 256, 0, stream>>>(x1, x2);
    gemm8_kernel<<<(NROWS / 256) * (NROWS / 256), 512, 0, stream>>>(out);
}

// Round 4
// 189.798 us; speedup vs baseline: 2.1624x; 2.1624x over previous
//
#include <hip/hip_runtime.h>
#include <hip/hip_bf16.h>

#define NROWS 8192
#define KD    1024

typedef __attribute__((ext_vector_type(8))) short bf16x8;
typedef __attribute__((ext_vector_type(4))) float f32x4;

__device__ unsigned short g_x1n[(size_t)NROWS * KD];
__device__ unsigned short g_x2n[(size_t)NROWS * KD];

__device__ __forceinline__ unsigned short f2bf(float f) {
    union { float f; unsigned u; } x; x.f = f;
    return (unsigned short)((x.u + 0x7fffu + ((x.u >> 16) & 1u)) >> 16);  // RNE
}

__global__ __launch_bounds__(256) void norm_cast_kernel(const float* __restrict__ x1,
                                                        const float* __restrict__ x2) {
    int row = blockIdx.x;
    const float* src;
    unsigned short* dst;
    if (row < NROWS) { src = x1 + (size_t)row * KD;           dst = g_x1n + (size_t)row * KD; }
    else             { src = x2 + (size_t)(row - NROWS) * KD; dst = g_x2n + (size_t)(row - NROWS) * KD; }

    int t = threadIdx.x;
    float4 v = ((const float4*)src)[t];
    float s = v.x * v.x + v.y * v.y + v.z * v.z + v.w * v.w;
    #pragma unroll
    for (int off = 32; off > 0; off >>= 1) s += __shfl_down(s, off);

    __shared__ float red[4];
    if ((t & 63) == 0) red[t >> 6] = s;
    __syncthreads();
    float tot = red[0] + red[1] + red[2] + red[3];
    float inv = 1.0f / fmaxf(sqrtf(tot), 1e-8f);

    ushort4 o;
    o.x = f2bf(v.x * inv); o.y = f2bf(v.y * inv);
    o.z = f2bf(v.z * inv); o.w = f2bf(v.w * inv);
    ((ushort4*)dst)[t] = o;
}

__device__ __forceinline__ void gload_lds16(const unsigned short* g, unsigned short* l) {
    __builtin_amdgcn_global_load_lds((const __attribute__((address_space(1))) void*)g,
                                     (__attribute__((address_space(3))) void*)l,
                                     16, 0, 0);
}

#define BARX() do { asm volatile("" ::: "memory"); __builtin_amdgcn_s_barrier(); \
                    asm volatile("" ::: "memory"); } while (0)
// Template-literal drain: single lgkmcnt(0) + sched_barrier(0) pins an
// uninterrupted MFMA burst (rule #18: MFMA must not hoist above the drain).
#define DRAIN_LDS() do { asm volatile("s_waitcnt lgkmcnt(0)" ::: "memory"); \
                         __builtin_amdgcn_sched_barrier(0); } while (0)
#define MFMA16(a, b, c) __builtin_amdgcn_mfma_f32_16x16x32_bf16((a), (b), (c), 0, 0, 0)

struct Ctx {
    const unsigned short* Ablk;
    const unsigned short* Bblk;
    unsigned short* ldsf;
    int t;
    int trow;                     // t>>3 (staging row 0..63)
    int scol;                     // pre-swizzled source col element offset
    int aoff0, aoff1, boff0, boff1;
    int wr, wch;
};

// Stage one half-tile (128 rows x 64 k): 2 x global_load_lds(16B) per thread.
// LDS dest LINEAR; global source carries the inverse swizzle (scol).
__device__ __forceinline__ void stage_half(const Ctx& c, const unsigned short* mat,
                                           int hbit, int region, int Tk) {
    const unsigned short* src = mat + (size_t)(hbit * 128 + c.trow) * KD + Tk * 64 + c.scol;
    unsigned short* dst = c.ldsf + region * 8192 + c.t * 8;
    gload_lds16(src, dst);
    gload_lds16(src + (size_t)64 * KD, dst + 4096);
}

// One K-tile (BK=64): 4 phases (C-quadrants), 16 MFMA each.
// Stage: q0 -> (T+1).A0, q1 -> (T+1).A1, q2 -> (T+2).B0, q3 -> (T+2).B1
template<int BUF, bool SA, bool SB, int WAITN>
__device__ __forceinline__ void tile_body(const Ctx& c, f32x4 (&acc)[8][4], int T) {
    const unsigned short* ab = c.ldsf + (BUF * 4 + 0) * 8192 + c.wr * 8192;
    const unsigned short* bb = c.ldsf + (BUF * 4 + 2) * 8192 + c.wch * 8192;
    bf16x8 Af[8], Bf[8];

    // ---- q0: read A mi0-3 (8) + B ni0-1 (4); MFMA mi0-3 x ni0-1 ----
    #pragma unroll
    for (int mi = 0; mi < 4; ++mi) {
        Af[mi * 2 + 0] = *(const bf16x8*)(ab + mi * 1024 + c.aoff0);
        Af[mi * 2 + 1] = *(const bf16x8*)(ab + mi * 1024 + c.aoff1);
    }
    #pragma unroll
    for (int ni = 0; ni < 2; ++ni) {
        Bf[ni * 2 + 0] = *(const bf16x8*)(bb + ni * 1024 + c.boff0);
        Bf[ni * 2 + 1] = *(const bf16x8*)(bb + ni * 1024 + c.boff1);
    }
    if (SA) stage_half(c, c.Ablk, 0, ((BUF ^ 1) * 4 + 0), T + 1);
    asm volatile("s_waitcnt lgkmcnt(8)" ::: "memory");   // 12-read phase pacing hint
    BARX();
    DRAIN_LDS();
    __builtin_amdgcn_s_setprio(1);
    #pragma unroll
    for (int mi = 0; mi < 4; ++mi)
        #pragma unroll
        for (int ni = 0; ni < 2; ++ni) {
            acc[mi][ni] = MFMA16(Af[mi * 2 + 0], Bf[ni * 2 + 0], acc[mi][ni]);
            acc[mi][ni] = MFMA16(Af[mi * 2 + 1], Bf[ni * 2 + 1], acc[mi][ni]);
        }
    __builtin_amdgcn_s_setprio(0);
    BARX();

    // ---- q1: read B ni2-3 (4); MFMA mi0-3 x ni2-3 ----
    #pragma unroll
    for (int ni = 2; ni < 4; ++ni) {
        Bf[ni * 2 + 0] = *(const bf16x8*)(bb + ni * 1024 + c.boff0);
        Bf[ni * 2 + 1] = *(const bf16x8*)(bb + ni * 1024 + c.boff1);
    }
    if (SA) stage_half(c, c.Ablk, 1, ((BUF ^ 1) * 4 + 1), T + 1);
    BARX();
    DRAIN_LDS();
    __builtin_amdgcn_s_setprio(1);
    #pragma unroll
    for (int mi = 0; mi < 4; ++mi)
        #pragma unroll
        for (int ni = 2; ni < 4; ++ni) {
            acc[mi][ni] = MFMA16(Af[mi * 2 + 0], Bf[ni * 2 + 0], acc[mi][ni]);
            acc[mi][ni] = MFMA16(Af[mi * 2 + 1], Bf[ni * 2 + 1], acc[mi][ni]);
        }
    __builtin_amdgcn_s_setprio(0);
    BARX();

    // ---- q2: read A mi4-7 (8, overwrite Af); MFMA mi4-7 x ni2-3 ----
    #pragma unroll
    for (int mi = 0; mi < 4; ++mi) {
        Af[mi * 2 + 0] = *(const bf16x8*)(ab + (mi + 4) * 1024 + c.aoff0);
        Af[mi * 2 + 1] = *(const bf16x8*)(ab + (mi + 4) * 1024 + c.aoff1);
    }
    if (SB) stage_half(c, c.Bblk, 0, (BUF * 4 + 2), T + 2);
    BARX();
    DRAIN_LDS();
    __builtin_amdgcn_s_setprio(1);
    #pragma unroll
    for (int mi = 0; mi < 4; ++mi)
        #pragma unroll
        for (int ni = 2; ni < 4; ++ni) {
            acc[mi + 4][ni] = MFMA16(Af[mi * 2 + 0], Bf[ni * 2 + 0], acc[mi + 4][ni]);
            acc[mi + 4][ni] = MFMA16(Af[mi * 2 + 1], Bf[ni * 2 + 1], acc[mi + 4][ni]);
        }
    __builtin_amdgcn_s_setprio(0);
    BARX();

    // ---- q3: 0 reads; MFMA mi4-7 x ni0-1 ----
    if (SB) stage_half(c, c.Bblk, 1, (BUF * 4 + 3), T + 2);
    BARX();
    DRAIN_LDS();
    __builtin_amdgcn_s_setprio(1);
    #pragma unroll
    for (int mi = 0; mi < 4; ++mi)
        #pragma unroll
        for (int ni = 0; ni < 2; ++ni) {
            acc[mi + 4][ni] = MFMA16(Af[mi * 2 + 0], Bf[ni * 2 + 0], acc[mi + 4][ni]);
            acc[mi + 4][ni] = MFMA16(Af[mi * 2 + 1], Bf[ni * 2 + 1], acc[mi + 4][ni]);
        }
    __builtin_amdgcn_s_setprio(0);
    if (WAITN == 4)      asm volatile("s_waitcnt vmcnt(4)" ::: "memory");
    else if (WAITN == 0) asm volatile("s_waitcnt vmcnt(0)" ::: "memory");
    BARX();
}

// 256x256 tile, BK=64, 8 waves (2M x 4N), 8-phase counted-vmcnt schedule.
__global__ __launch_bounds__(512, 2) void gemm8_kernel(float* __restrict__ C) {
    __shared__ unsigned short lds[2][4][8192];   // 128 KiB

    int bid = blockIdx.x;                 // 1024 blocks, 1024 % 8 == 0
    int swz = (bid & 7) * 128 + (bid >> 3);
    int bm = swz >> 5, bn = swz & 31;

    int t = threadIdx.x;
    int lane = t & 63, wid = t >> 6;
    int wr = wid >> 2, wc = wid & 3;
    int r = lane & 15;
    int s0 = (lane >> 4) ^ (r & 7);       // swizzled 16B slot, kk=0
    int s1 = s0 ^ 4;                      // kk=1

    Ctx c;
    c.Ablk = g_x1n + (size_t)bm * 256 * KD;
    c.Bblk = g_x2n + (size_t)bn * 256 * KD;
    c.ldsf = &lds[0][0][0];
    c.t = t;
    c.trow = t >> 3;
    c.scol = (((t & 7) ^ ((t >> 3) & 7))) * 8;   // inverse swizzle on global source
    c.aoff0 = r * 64 + s0 * 8;
    c.aoff1 = r * 64 + s1 * 8;
    c.boff0 = ((wc & 1) * 64 + r) * 64 + s0 * 8;
    c.boff1 = ((wc & 1) * 64 + r) * 64 + s1 * 8;
    c.wr = wr;
    c.wch = wc >> 1;

    f32x4 acc[8][4] = {};

    // Prologue: tile0 {B0,B1,A0,A1}, tile1 {B0,B1}; wait tile0 complete.
    stage_half(c, c.Bblk, 0, 2, 0);
    stage_half(c, c.Bblk, 1, 3, 0);
    stage_half(c, c.Ablk, 0, 0, 0);
    stage_half(c, c.Ablk, 1, 1, 0);
    stage_half(c, c.Bblk, 0, 6, 1);
    stage_half(c, c.Bblk, 1, 7, 1);
    asm volatile("s_waitcnt vmcnt(4)" ::: "memory");
    BARX();

    for (int it = 0; it < 7; ++it) {      // tiles 0..13, full staging
        tile_body<0, true, true, 4>(c, acc, 2 * it);
        tile_body<1, true, true, 4>(c, acc, 2 * it + 1);
    }
    tile_body<0, true, false, 0>(c, acc, 14);   // stages (15).A0/A1, drain
    tile_body<1, false, false, -1>(c, acc, 15);

    // Epilogue: C/D layout col = lane&15, row = (lane>>4)*4 + j.
    // Non-temporal stores: C (262 MB/call) must not evict the 32 MB panels from L3.
    int cn = lane & 15, rq = (lane >> 4) * 4;
    int rbase = bm * 256 + wr * 128;
    int cbase = bn * 256 + wc * 64;
    #pragma unroll
    for (int mi = 0; mi < 8; ++mi)
        #pragma unroll
        for (int ni = 0; ni < 4; ++ni)
            #pragma unroll
            for (int j = 0; j < 4; ++j)
                __builtin_nontemporal_store(acc[mi][ni][j] * 20.0f,
                    &C[(size_t)(rbase + mi * 16 + rq + j) * NROWS + cbase + ni * 16 + cn]);
}

extern "C" void kernel_launch(void* const* d_in, const int* in_sizes, int n_in,
                              void* d_out, int out_size, void* d_ws, size_t ws_size,
                              hipStream_t stream) {
    (void)in_sizes; (void)n_in; (void)d_ws; (void)ws_size; (void)out_size;
    const float* x1 = (const float*)d_in[0];
    const float* x2 = (const float*)d_in[1];
    float* out = (float*)d_out;

    norm_cast_kernel<<<2 * NROWS, 256, 0, stream>>>(x1, x2);
    gemm8_kernel<<<(NROWS / 256) * (NROWS / 256), 512, 0, stream>>>(out);
}

// Round 5
// 175.062 us; speedup vs baseline: 2.3445x; 1.0842x over previous
//
#include <hip/hip_runtime.h>
#include <hip/hip_bf16.h>

#define NROWS 8192
#define KD    1024

typedef __attribute__((ext_vector_type(8))) short bf16x8;
typedef __attribute__((ext_vector_type(4))) float f32x4;

__device__ unsigned short g_x1n[(size_t)NROWS * KD];
__device__ unsigned short g_x2n[(size_t)NROWS * KD];

__device__ __forceinline__ unsigned short f2bf(float f) {
    union { float f; unsigned u; } x; x.f = f;
    return (unsigned short)((x.u + 0x7fffu + ((x.u >> 16) & 1u)) >> 16);  // RNE
}

__global__ __launch_bounds__(256) void norm_cast_kernel(const float* __restrict__ x1,
                                                        const float* __restrict__ x2) {
    int row = blockIdx.x;
    const float* src;
    unsigned short* dst;
    if (row < NROWS) { src = x1 + (size_t)row * KD;           dst = g_x1n + (size_t)row * KD; }
    else             { src = x2 + (size_t)(row - NROWS) * KD; dst = g_x2n + (size_t)(row - NROWS) * KD; }

    int t = threadIdx.x;
    float4 v = ((const float4*)src)[t];
    float s = v.x * v.x + v.y * v.y + v.z * v.z + v.w * v.w;
    #pragma unroll
    for (int off = 32; off > 0; off >>= 1) s += __shfl_down(s, off);

    __shared__ float red[4];
    if ((t & 63) == 0) red[t >> 6] = s;
    __syncthreads();
    float tot = red[0] + red[1] + red[2] + red[3];
    float inv = 1.0f / fmaxf(sqrtf(tot), 1e-8f);

    ushort4 o;
    o.x = f2bf(v.x * inv); o.y = f2bf(v.y * inv);
    o.z = f2bf(v.z * inv); o.w = f2bf(v.w * inv);
    ((ushort4*)dst)[t] = o;
}

__device__ __forceinline__ void gload_lds16(const unsigned short* g, unsigned short* l) {
    __builtin_amdgcn_global_load_lds((const __attribute__((address_space(1))) void*)g,
                                     (__attribute__((address_space(3))) void*)l,
                                     16, 0, 0);
}

#define BARX() do { asm volatile("" ::: "memory"); __builtin_amdgcn_s_barrier(); \
                    asm volatile("" ::: "memory"); } while (0)
// Template-literal drain: single lgkmcnt(0) + sched_barrier(0) pins an
// uninterrupted MFMA burst (rule #18: MFMA must not hoist above the drain).
#define DRAIN_LDS() do { asm volatile("s_waitcnt lgkmcnt(0)" ::: "memory"); \
                         __builtin_amdgcn_sched_barrier(0); } while (0)
#define MFMA16(a, b, c) __builtin_amdgcn_mfma_f32_16x16x32_bf16((a), (b), (c), 0, 0, 0)

struct Ctx {
    const unsigned short* Ablk;
    const unsigned short* Bblk;
    unsigned short* ldsf;
    int t;
    int trow;                     // t>>3 (staging row 0..63)
    int scol;                     // pre-swizzled source col element offset
    int aoff0, aoff1, boff0, boff1;
    int wr, wch;
};

// Stage one half-tile (128 rows x 64 k): 2 x global_load_lds(16B) per thread.
// LDS dest LINEAR; global source carries the inverse swizzle (scol).
__device__ __forceinline__ void stage_half(const Ctx& c, const unsigned short* mat,
                                           int hbit, int region, int Tk) {
    const unsigned short* src = mat + (size_t)(hbit * 128 + c.trow) * KD + Tk * 64 + c.scol;
    unsigned short* dst = c.ldsf + region * 8192 + c.t * 8;
    gload_lds16(src, dst);
    gload_lds16(src + (size_t)64 * KD, dst + 4096);
}

// One K-tile (BK=64): 4 phases (C-quadrants), 16 MFMA each.
// Stage: q0 -> (T+1).A0, q1 -> (T+1).A1, q2 -> (T+2).B0, q3 -> (T+2).B1
template<int BUF, bool SA, bool SB, int WAITN>
__device__ __forceinline__ void tile_body(const Ctx& c, f32x4 (&acc)[8][4], int T) {
    const unsigned short* ab = c.ldsf + (BUF * 4 + 0) * 8192 + c.wr * 8192;
    const unsigned short* bb = c.ldsf + (BUF * 4 + 2) * 8192 + c.wch * 8192;
    bf16x8 Af[8], Bf[8];

    // ---- q0: read A mi0-3 (8) + B ni0-1 (4); MFMA mi0-3 x ni0-1 ----
    #pragma unroll
    for (int mi = 0; mi < 4; ++mi) {
        Af[mi * 2 + 0] = *(const bf16x8*)(ab + mi * 1024 + c.aoff0);
        Af[mi * 2 + 1] = *(const bf16x8*)(ab + mi * 1024 + c.aoff1);
    }
    #pragma unroll
    for (int ni = 0; ni < 2; ++ni) {
        Bf[ni * 2 + 0] = *(const bf16x8*)(bb + ni * 1024 + c.boff0);
        Bf[ni * 2 + 1] = *(const bf16x8*)(bb + ni * 1024 + c.boff1);
    }
    if (SA) stage_half(c, c.Ablk, 0, ((BUF ^ 1) * 4 + 0), T + 1);
    asm volatile("s_waitcnt lgkmcnt(8)" ::: "memory");   // 12-read phase pacing hint
    BARX();
    DRAIN_LDS();
    __builtin_amdgcn_s_setprio(1);
    #pragma unroll
    for (int mi = 0; mi < 4; ++mi)
        #pragma unroll
        for (int ni = 0; ni < 2; ++ni) {
            acc[mi][ni] = MFMA16(Af[mi * 2 + 0], Bf[ni * 2 + 0], acc[mi][ni]);
            acc[mi][ni] = MFMA16(Af[mi * 2 + 1], Bf[ni * 2 + 1], acc[mi][ni]);
        }
    __builtin_amdgcn_s_setprio(0);
    BARX();

    // ---- q1: read B ni2-3 (4); MFMA mi0-3 x ni2-3 ----
    #pragma unroll
    for (int ni = 2; ni < 4; ++ni) {
        Bf[ni * 2 + 0] = *(const bf16x8*)(bb + ni * 1024 + c.boff0);
        Bf[ni * 2 + 1] = *(const bf16x8*)(bb + ni * 1024 + c.boff1);
    }
    if (SA) stage_half(c, c.Ablk, 1, ((BUF ^ 1) * 4 + 1), T + 1);
    BARX();
    DRAIN_LDS();
    __builtin_amdgcn_s_setprio(1);
    #pragma unroll
    for (int mi = 0; mi < 4; ++mi)
        #pragma unroll
        for (int ni = 2; ni < 4; ++ni) {
            acc[mi][ni] = MFMA16(Af[mi * 2 + 0], Bf[ni * 2 + 0], acc[mi][ni]);
            acc[mi][ni] = MFMA16(Af[mi * 2 + 1], Bf[ni * 2 + 1], acc[mi][ni]);
        }
    __builtin_amdgcn_s_setprio(0);
    BARX();

    // ---- q2: read A mi4-7 (8, overwrite Af); MFMA mi4-7 x ni2-3 ----
    #pragma unroll
    for (int mi = 0; mi < 4; ++mi) {
        Af[mi * 2 + 0] = *(const bf16x8*)(ab + (mi + 4) * 1024 + c.aoff0);
        Af[mi * 2 + 1] = *(const bf16x8*)(ab + (mi + 4) * 1024 + c.aoff1);
    }
    if (SB) stage_half(c, c.Bblk, 0, (BUF * 4 + 2), T + 2);
    BARX();
    DRAIN_LDS();
    __builtin_amdgcn_s_setprio(1);
    #pragma unroll
    for (int mi = 0; mi < 4; ++mi)
        #pragma unroll
        for (int ni = 2; ni < 4; ++ni) {
            acc[mi + 4][ni] = MFMA16(Af[mi * 2 + 0], Bf[ni * 2 + 0], acc[mi + 4][ni]);
            acc[mi + 4][ni] = MFMA16(Af[mi * 2 + 1], Bf[ni * 2 + 1], acc[mi + 4][ni]);
        }
    __builtin_amdgcn_s_setprio(0);
    BARX();

    // ---- q3: 0 reads; MFMA mi4-7 x ni0-1 ----
    if (SB) stage_half(c, c.Bblk, 1, (BUF * 4 + 3), T + 2);
    BARX();
    DRAIN_LDS();
    __builtin_amdgcn_s_setprio(1);
    #pragma unroll
    for (int mi = 0; mi < 4; ++mi)
        #pragma unroll
        for (int ni = 0; ni < 2; ++ni) {
            acc[mi + 4][ni] = MFMA16(Af[mi * 2 + 0], Bf[ni * 2 + 0], acc[mi + 4][ni]);
            acc[mi + 4][ni] = MFMA16(Af[mi * 2 + 1], Bf[ni * 2 + 1], acc[mi + 4][ni]);
        }
    __builtin_amdgcn_s_setprio(0);
    if (WAITN == 4)      asm volatile("s_waitcnt vmcnt(4)" ::: "memory");
    else if (WAITN == 0) asm volatile("s_waitcnt vmcnt(0)" ::: "memory");
    BARX();
}

// 256x256 tile, BK=64, 8 waves (2M x 4N), 8-phase counted-vmcnt schedule.
__global__ __launch_bounds__(512, 2) void gemm8_kernel(float* __restrict__ C) {
    __shared__ unsigned short lds[2][4][8192];   // 128 KiB

    // L2-rectangle XCD mapping (bijective): each XCD's 32 concurrent blocks
    // cover a 4(bm) x 8(bn) rectangle (A 2MB + B 4MB active, fits 4MB L2 much
    // better than 16MB of B); the XCD's bn-band is pinned across all 4 rounds
    // so its B panels stay L2-resident.
    int bid = blockIdx.x;                 // 1024 blocks
    int xcd  = bid & 7;
    int idx  = bid >> 3;                  // 0..127, launch order within XCD
    int rnd  = idx >> 5;                  // 0..3
    int j    = idx & 31;                  // 0..31
    int rect = rnd * 8 + xcd;             // 0..31
    int bm = (rect >> 2) * 4 + (j >> 3);  // 8 bm-bands of 4
    int bn = (rect & 3) * 8 + (j & 7);    // 4 bn-bands of 8 (fixed per XCD)

    int t = threadIdx.x;
    int lane = t & 63, wid = t >> 6;
    int wr = wid >> 2, wc = wid & 3;
    int r = lane & 15;
    int s0 = (lane >> 4) ^ (r & 7);       // swizzled 16B slot, kk=0
    int s1 = s0 ^ 4;                      // kk=1

    Ctx c;
    c.Ablk = g_x1n + (size_t)bm * 256 * KD;
    c.Bblk = g_x2n + (size_t)bn * 256 * KD;
    c.ldsf = &lds[0][0][0];
    c.t = t;
    c.trow = t >> 3;
    c.scol = (((t & 7) ^ ((t >> 3) & 7))) * 8;   // inverse swizzle on global source
    c.aoff0 = r * 64 + s0 * 8;
    c.aoff1 = r * 64 + s1 * 8;
    c.boff0 = ((wc & 1) * 64 + r) * 64 + s0 * 8;
    c.boff1 = ((wc & 1) * 64 + r) * 64 + s1 * 8;
    c.wr = wr;
    c.wch = wc >> 1;

    f32x4 acc[8][4] = {};

    // Prologue: tile0 {B0,B1,A0,A1}, tile1 {B0,B1}; wait tile0 complete.
    stage_half(c, c.Bblk, 0, 2, 0);
    stage_half(c, c.Bblk, 1, 3, 0);
    stage_half(c, c.Ablk, 0, 0, 0);
    stage_half(c, c.Ablk, 1, 1, 0);
    stage_half(c, c.Bblk, 0, 6, 1);
    stage_half(c, c.Bblk, 1, 7, 1);
    asm volatile("s_waitcnt vmcnt(4)" ::: "memory");
    BARX();

    for (int it = 0; it < 7; ++it) {      // tiles 0..13, full staging
        tile_body<0, true, true, 4>(c, acc, 2 * it);
        tile_body<1, true, true, 4>(c, acc, 2 * it + 1);
    }
    tile_body<0, true, false, 0>(c, acc, 14);   // stages (15).A0/A1, drain
    tile_body<1, false, false, -1>(c, acc, 15);

    // Epilogue: C/D layout col = lane&15, row = (lane>>4)*4 + j. Plain stores
    // (L2 write-combining merges the 4B stores; nontemporal was +49% WRITE_SIZE).
    int cn = lane & 15, rq = (lane >> 4) * 4;
    int rbase = bm * 256 + wr * 128;
    int cbase = bn * 256 + wc * 64;
    #pragma unroll
    for (int mi = 0; mi < 8; ++mi)
        #pragma unroll
        for (int ni = 0; ni < 4; ++ni)
            #pragma unroll
            for (int j2 = 0; j2 < 4; ++j2)
                C[(size_t)(rbase + mi * 16 + rq + j2) * NROWS + cbase + ni * 16 + cn] =
                    acc[mi][ni][j2] * 20.0f;
}

extern "C" void kernel_launch(void* const* d_in, const int* in_sizes, int n_in,
                              void* d_out, int out_size, void* d_ws, size_t ws_size,
                              hipStream_t stream) {
    (void)in_sizes; (void)n_in; (void)d_ws; (void)ws_size; (void)out_size;
    const float* x1 = (const float*)d_in[0];
    const float* x2 = (const float*)d_in[1];
    float* out = (float*)d_out;

    norm_cast_kernel<<<2 * NROWS, 256, 0, stream>>>(x1, x2);
    gemm8_kernel<<<(NROWS / 256) * (NROWS / 256), 512, 0, stream>>>(out);
}